// Round 7
// baseline (512.772 us; speedup 1.0000x reference)
//
#include <hip/hip_runtime.h>
#include <hip/hip_bf16.h>
#include <cstddef>
#include <cstdint>

// Problem constants
#define NB 16
#define NC 1024
#define NF 4096
#define CIN 256
#define CSKIP 128
#define HW_ 512
#define K1 (CIN + CSKIP)                  // 384
#define M_ROWS (NB * NF)                  // 65536
#define H_ELEMS ((size_t)M_ROWS * HW_)    // 33554432
#define POS_ELEMS (M_ROWS * 3)            // 196608

#define QB 64      // queries per kNN block
#define PARTS 4    // candidate quarters per query

typedef __attribute__((ext_vector_type(8))) short bf16x8;
typedef __attribute__((ext_vector_type(4))) float f32x4;
typedef __attribute__((ext_vector_type(4))) unsigned int u32x4;

__device__ __forceinline__ unsigned short f2bf(float f) {
    union { __hip_bfloat16 h; unsigned short u; } cv;
    cv.h = __float2bfloat16(f);
    return cv.u;
}
__device__ __forceinline__ float bf2f(unsigned short u) {
    union { __hip_bfloat16 h; unsigned short u; } cv;
    cv.u = u;
    return __bfloat162float(cv.h);
}
__device__ __forceinline__ void split2(float v, unsigned short& hi, unsigned short& lo) {
    hi = f2bf(v);
    lo = f2bf(v - bf2f(hi));
}

#define GLOAD_LDS(gsrc, ldst)                                                            \
    __builtin_amdgcn_global_load_lds((const __attribute__((address_space(1))) void*)(gsrc), \
                                     (__attribute__((address_space(3))) void*)(ldst), 16, 0, 0)

// ---------------------------------------------------------------------------
// Kernel 1: kNN (K=3) + inverse-distance interpolation (unchanged).
// ---------------------------------------------------------------------------
__launch_bounds__(256)
__global__ void knn_interp_kernel(const float* __restrict__ x,
                                  const float* __restrict__ pos,
                                  const float* __restrict__ pos_skip,
                                  unsigned short* __restrict__ Ahi,
                                  unsigned short* __restrict__ Alo)
{
    __shared__ float4 sp4[NC];
    __shared__ float  s_b[QB * PARTS * 3];
    __shared__ int    s_i[QB * PARTS * 3];
    __shared__ int    s_idx[QB * 3];
    __shared__ float  s_w[QB * 3];

    const int tid   = threadIdx.x;
    const int cloud = blockIdx.x >> 6;
    const int chunk = blockIdx.x & 63;

    const float* pbase = pos + (size_t)cloud * NC * 3;
    for (int j = tid; j < NC; j += 256) {
        const float px = pbase[3 * j + 0];
        const float py = pbase[3 * j + 1];
        const float pz = pbase[3 * j + 2];
        sp4[j] = make_float4(px, py, pz, px * px + py * py + pz * pz);
    }
    __syncthreads();

    const int q    = tid & (QB - 1);
    const int part = tid >> 6;
    const float* qp = pos_skip + ((size_t)cloud * NF + chunk * QB + q) * 3;
    const float qx = qp[0], qy = qp[1], qz = qp[2];
    const float ax = -2.f * qx, ay = -2.f * qy, az = -2.f * qz;
    const float qq = qx * qx + qy * qy + qz * qz;

    float b0 = 1e30f, b1 = 1e30f, b2 = 1e30f;
    int   i0 = 0,     i1 = 0,     i2 = 0;
    const int jbase = part * (NC / PARTS);
#pragma unroll 4
    for (int jj = 0; jj < NC / PARTS; ++jj) {
        const int j = jbase + jj;
        const float4 p = sp4[j];
        const float d = fmaf(ax, p.x, fmaf(ay, p.y, fmaf(az, p.z, p.w))) + qq;
        const bool c0 = d < b0, c1 = d < b1, c2 = d < b2;
        const float nb0 = fminf(b0, d);
        const float nb1 = __builtin_amdgcn_fmed3f(b0, b1, d);
        const float nb2 = __builtin_amdgcn_fmed3f(b1, b2, d);
        const int ni0 = c0 ? j : i0;
        const int ni1 = c0 ? i0 : (c1 ? j : i1);
        const int ni2 = c1 ? i1 : (c2 ? j : i2);
        b0 = nb0; b1 = nb1; b2 = nb2;
        i0 = ni0; i1 = ni1; i2 = ni2;
    }
    {
        const int pb = (q * PARTS + part) * 3;
        s_b[pb + 0] = b0; s_b[pb + 1] = b1; s_b[pb + 2] = b2;
        s_i[pb + 0] = i0; s_i[pb + 1] = i1; s_i[pb + 2] = i2;
    }
    __syncthreads();

    if (tid < QB) {
        const int base = tid * PARTS * 3;
        float m0 = s_b[base + 0], m1 = s_b[base + 1], m2 = s_b[base + 2];
        int   a0 = s_i[base + 0], a1 = s_i[base + 1], a2 = s_i[base + 2];
#pragma unroll
        for (int p = 1; p < PARTS; ++p) {
#pragma unroll
            for (int s = 0; s < 3; ++s) {
                const float d = s_b[base + p * 3 + s];
                const int   j = s_i[base + p * 3 + s];
                const bool c0 = d < m0, c1 = d < m1, c2 = d < m2;
                const float n0 = fminf(m0, d);
                const float n1 = __builtin_amdgcn_fmed3f(m0, m1, d);
                const float n2 = __builtin_amdgcn_fmed3f(m1, m2, d);
                const int e0 = c0 ? j : a0;
                const int e1 = c0 ? a0 : (c1 ? j : a1);
                const int e2 = c1 ? a1 : (c2 ? j : a2);
                m0 = n0; m1 = n1; m2 = n2;
                a0 = e0; a1 = e1; a2 = e2;
            }
        }
        const int id[3] = {a0, a1, a2};
        float w[3], tw = 0.f;
#pragma unroll
        for (int s = 0; s < 3; ++s) {
            const float4 p = sp4[id[s]];
            const float dx = qx - p.x, dy = qy - p.y, dz = qz - p.z;
            const float d2 = fmaf(dx, dx, fmaf(dy, dy, dz * dz));
            w[s] = 1.f / fmaxf(d2, 1e-16f);
            tw += w[s];
        }
        const float winv = 1.f / tw;
#pragma unroll
        for (int s = 0; s < 3; ++s) {
            s_idx[tid * 3 + s] = id[s];
            s_w[tid * 3 + s]   = w[s] * winv;
        }
    }
    __syncthreads();

    const int wave = tid >> 6, lane = tid & 63;
    const float* xc = x + (size_t)cloud * NC * CIN;
    const size_t rowbase = (size_t)cloud * NF + chunk * QB;
    for (int qq2 = wave; qq2 < QB; qq2 += 4) {
        const int   j0 = s_idx[qq2 * 3 + 0], j1 = s_idx[qq2 * 3 + 1], j2 = s_idx[qq2 * 3 + 2];
        const float u0 = s_w[qq2 * 3 + 0],   u1 = s_w[qq2 * 3 + 1],   u2 = s_w[qq2 * 3 + 2];
        const float4 f0 = ((const float4*)(xc + (size_t)j0 * CIN))[lane];
        const float4 f1 = ((const float4*)(xc + (size_t)j1 * CIN))[lane];
        const float4 f2 = ((const float4*)(xc + (size_t)j2 * CIN))[lane];
        float o[4];
        o[0] = u0 * f0.x + u1 * f1.x + u2 * f2.x;
        o[1] = u0 * f0.y + u1 * f1.y + u2 * f2.y;
        o[2] = u0 * f0.z + u1 * f1.z + u2 * f2.z;
        o[3] = u0 * f0.w + u1 * f1.w + u2 * f2.w;
        unsigned short h[4], l[4];
#pragma unroll
        for (int c = 0; c < 4; ++c) split2(o[c], h[c], l[c]);
        uint2 hv, lv;
        hv.x = (unsigned)h[0] | ((unsigned)h[1] << 16);
        hv.y = (unsigned)h[2] | ((unsigned)h[3] << 16);
        lv.x = (unsigned)l[0] | ((unsigned)l[1] << 16);
        lv.y = (unsigned)l[2] | ((unsigned)l[3] << 16);
        const size_t ro = (rowbase + qq2) * K1;
        ((uint2*)(Ahi + ro))[lane] = hv;
        ((uint2*)(Alo + ro))[lane] = lv;
    }
}

// ---------------------------------------------------------------------------
// Kernel 2: x_skip -> split planes at columns 256..383 of A1.
// ---------------------------------------------------------------------------
__launch_bounds__(256)
__global__ void conv_skip_kernel(const float* __restrict__ xs,
                                 unsigned short* __restrict__ Ahi,
                                 unsigned short* __restrict__ Alo)
{
    const int idx = blockIdx.x * 256 + threadIdx.x;
    const int row = idx >> 5;
    const int c4  = idx & 31;
    const float4 v = ((const float4*)(xs + (size_t)row * CSKIP))[c4];
    const float o[4] = {v.x, v.y, v.z, v.w};
    unsigned short h[4], l[4];
#pragma unroll
    for (int c = 0; c < 4; ++c) split2(o[c], h[c], l[c]);
    uint2 hv, lv;
    hv.x = (unsigned)h[0] | ((unsigned)h[1] << 16);
    hv.y = (unsigned)h[2] | ((unsigned)h[3] << 16);
    lv.x = (unsigned)l[0] | ((unsigned)l[1] << 16);
    lv.y = (unsigned)l[2] | ((unsigned)l[3] << 16);
    const size_t off = (size_t)row * K1 + CIN + c4 * 4;
    *(uint2*)(Ahi + off) = hv;
    *(uint2*)(Alo + off) = lv;
}

// ---------------------------------------------------------------------------
// Kernel 3: weight transpose + split -> WT planes [512][Kd].
// ---------------------------------------------------------------------------
__launch_bounds__(256)
__global__ void conv_w_kernel(const float* __restrict__ w,
                              unsigned short* __restrict__ WhiT,
                              unsigned short* __restrict__ WloT, int Kd)
{
    const int idx = blockIdx.x * 256 + threadIdx.x;
    if (idx >= Kd * 512) return;
    const int k = idx >> 9;
    const int n = idx & 511;
    const float v = w[(size_t)k * 512 + n];
    unsigned short h, l;
    split2(v, h, l);
    WhiT[(size_t)n * Kd + k] = h;
    WloT[(size_t)n * Kd + k] = l;
}

// ---------------------------------------------------------------------------
// Kernel 4 (v3): bf16 split NT-GEMM. A (hi/lo) staged via global_load_lds
// into LDS (dbuf, 32KB); W (hi/lo) fragments loaded DIRECTLY global->regs
// (L2-resident, dbuf one K-tile ahead, explicit ping-pong register sets).
// Halves LDS read traffic per MFMA (the round-5 bottleneck).
// Epilogue: acc -> packed-u32 LDS C-tile -> coalesced global stores.
// ---------------------------------------------------------------------------
__device__ __forceinline__ int cswz(int row) {
    return (((row >> 2) & 3) << 2) ^ (((row >> 3) & 1) << 1) ^ ((row >> 4) & 1);
}

template <bool SPLIT_OUT>
__launch_bounds__(256, 2)
__global__ void gemm_bf3s(const unsigned short* __restrict__ Ahi,
                          const unsigned short* __restrict__ Alo,
                          const unsigned short* __restrict__ Whi,   // [512][K]
                          const unsigned short* __restrict__ Wlo,
                          int K,
                          const float* __restrict__ bias,
                          const float* __restrict__ gamma,
                          const float* __restrict__ beta,
                          const float* __restrict__ mean,
                          const float* __restrict__ var,
                          float* __restrict__ Cf,
                          unsigned short* __restrict__ Chi,
                          unsigned short* __restrict__ Clo)
{
    __shared__ alignas(16) unsigned char smem[65536];  // loop uses 32KB; epilogue 64KB

    // XCD swizzle: 4 N-blocks of an M-panel land consecutively on one XCD.
    const int bid  = blockIdx.x;
    const int xcd  = bid & 7;
    const int slot = bid >> 3;
    const int bx   = slot & 3;
    const int by   = xcd + (slot >> 2) * 8;
    const int bm   = by * 128;
    const int bn   = bx * 128;

    const int tid  = threadIdx.x;
    const int lane = tid & 63;
    const int wv   = tid >> 6;
    const int wr   = wv >> 1;
    const int wc   = wv & 1;

    const int sr  = lane >> 2;      // staging row within 16-row chunk
    const int sgp = lane & 3;       // staging physical granule

    f32x4 acc[4][4];
#pragma unroll
    for (int i = 0; i < 4; ++i)
#pragma unroll
        for (int j = 0; j < 4; ++j) acc[i][j] = (f32x4){0.f, 0.f, 0.f, 0.f};

    // A staging: hi plane at buf*8192, lo plane at 16384 + buf*8192
    auto stage = [&](int buf, int kk) {
#pragma unroll
        for (int i = 0; i < 2; ++i) {
            const int rl = (wv * 2 + i) * 16 + sr;                  // 0..127
            const int g  = sgp ^ ((rl >> 1) & 3);
            const unsigned dst = (wv * 2 + i) * 1024 + buf * 8192;
            const size_t ro = (size_t)(bm + rl) * K + kk + g * 8;
            GLOAD_LDS(Ahi + ro, smem + dst);
            GLOAD_LDS(Alo + ro, smem + 16384 + dst);
        }
    };

    // W fragments: direct global->reg (same logical layout as LDS path)
    const int klane = (lane >> 4) * 8;
    auto loadB = [&](int kk, bf16x8* wh, bf16x8* wl) {
#pragma unroll
        for (int j = 0; j < 4; ++j) {
            const size_t c = (size_t)(bn + wc * 64 + j * 16 + (lane & 15));
            wh[j] = *(const bf16x8*)(Whi + c * K + kk + klane);
            wl[j] = *(const bf16x8*)(Wlo + c * K + kk + klane);
        }
    };

    auto compute = [&](int buf, const bf16x8* wh, const bf16x8* wl) {
        const unsigned short* sAh = (const unsigned short*)(smem + buf * 8192);
        const unsigned short* sAl = (const unsigned short*)(smem + 16384 + buf * 8192);
        bf16x8 ah[4], al[4];
#pragma unroll
        for (int i = 0; i < 4; ++i) {
            const int r  = wr * 64 + i * 16 + (lane & 15);
            const int ga = (lane >> 4) ^ ((r >> 1) & 3);
            ah[i] = *(const bf16x8*)(sAh + r * 32 + ga * 8);
            al[i] = *(const bf16x8*)(sAl + r * 32 + ga * 8);
        }
#pragma unroll
        for (int i = 0; i < 4; ++i)
#pragma unroll
            for (int j = 0; j < 4; ++j)
                acc[i][j] = __builtin_amdgcn_mfma_f32_16x16x32_bf16(ah[i], wh[j], acc[i][j], 0, 0, 0);
#pragma unroll
        for (int i = 0; i < 4; ++i)
#pragma unroll
            for (int j = 0; j < 4; ++j)
                acc[i][j] = __builtin_amdgcn_mfma_f32_16x16x32_bf16(ah[i], wl[j], acc[i][j], 0, 0, 0);
#pragma unroll
        for (int i = 0; i < 4; ++i)
#pragma unroll
            for (int j = 0; j < 4; ++j)
                acc[i][j] = __builtin_amdgcn_mfma_f32_16x16x32_bf16(al[i], wh[j], acc[i][j], 0, 0, 0);
    };

    bf16x8 whA[4], wlA[4], whB[4], wlB[4];
    loadB(0, whA, wlA);
    stage(0, 0);
    int buf = 0;
    const int NT = K / 32;                       // 12 or 16 (even)
    for (int t = 0; t < NT; t += 2) {
        __syncthreads();                         // tile t ready (drains vmcnt)
        if (t + 1 < NT) { stage(buf ^ 1, (t + 1) * 32); loadB((t + 1) * 32, whB, wlB); }
        compute(buf, whA, wlA);
        buf ^= 1;
        __syncthreads();                         // tile t+1 ready
        if (t + 2 < NT) { stage(buf ^ 1, (t + 2) * 32); loadB((t + 2) * 32, whA, wlA); }
        compute(buf, whB, wlB);
        buf ^= 1;
    }

    // ---- epilogue: BN -> packed u32 LDS C-tile -> coalesced global stores
    __syncthreads();                            // all ds_reads of last tile done
    unsigned int* sC = (unsigned int*)smem;     // [128][128] u32 (64KB)

    const int lc  = lane & 15;
    const int lr4 = (lane >> 4) * 4;
#pragma unroll
    for (int j = 0; j < 4; ++j) {
        const int col  = wc * 64 + j * 16 + lc;            // tile-local col
        const int colg = bn + col;
        const float s  = gamma[colg] / sqrtf(var[colg] + 1e-5f);
        const float sh = beta[colg] - mean[colg] * s;
        const float bb = bias[colg];
        const int g    = col >> 2;
#pragma unroll
        for (int i = 0; i < 4; ++i) {
            const f32x4 v = acc[i][j];
#pragma unroll
            for (int q = 0; q < 4; ++q) {
                const int row = wr * 64 + i * 16 + lr4 + q;
                const float val = fmaxf(v[q] + bb, 0.f) * s + sh;
                unsigned u;
                if (SPLIT_OUT) {
                    unsigned short h, l;
                    split2(val, h, l);
                    u = (unsigned)h | ((unsigned)l << 16);
                } else {
                    u = __float_as_uint(val);
                }
                sC[row * 128 + ((g ^ cswz(row)) << 2) + (col & 3)] = u;
            }
        }
    }
    __syncthreads();

    // reader: per iter, 2 rows x 32 granules -> 256B contiguous per row-plane
#pragma unroll
    for (int it = 0; it < 16; ++it) {
        const int row = wv * 32 + it * 2 + (lane >> 5);
        const int g   = lane & 31;
        const u32x4 v = *(const u32x4*)(sC + row * 128 + ((g ^ cswz(row)) << 2));
        const size_t rg = (size_t)(bm + row) * HW_ + bn + g * 4;
        if (SPLIT_OUT) {
            uint2 hv, lv;
            hv.x = (v[0] & 0xffffu) | (v[1] << 16);
            hv.y = (v[2] & 0xffffu) | (v[3] << 16);
            lv.x = (v[0] >> 16) | (v[1] & 0xffff0000u);
            lv.y = (v[2] >> 16) | (v[3] & 0xffff0000u);
            *(uint2*)(Chi + rg) = hv;
            *(uint2*)(Clo + rg) = lv;
        } else {
            *(u32x4*)((unsigned int*)Cf + rg) = v;
        }
    }
}

// ---------------------------------------------------------------------------
// Kernel 5: tail outputs (runs LAST; reclaims W2^T scratch in the tail region).
// ---------------------------------------------------------------------------
__launch_bounds__(256)
__global__ void tail_kernel(const float* __restrict__ pos_skip,
                            float* __restrict__ outp, int mode)
{
    const int i = blockIdx.x * 256 + threadIdx.x;
    if (i < POS_ELEMS) outp[i] = pos_skip[i];
    const int bi = i - POS_ELEMS;
    if (bi >= 0 && bi < M_ROWS) {
        if (mode == 0) {
            outp[POS_ELEMS + bi] = (float)(bi >> 12);
        } else {
            ((unsigned long long*)(outp + POS_ELEMS))[bi] = (unsigned long long)(bi >> 12);
        }
    }
}

// ---------------------------------------------------------------------------
extern "C" void kernel_launch(void* const* d_in, const int* in_sizes, int n_in,
                              void* d_out, int out_size, void* d_ws, size_t ws_size,
                              hipStream_t stream)
{
    const float* x        = (const float*)d_in[0];
    const float* pos      = (const float*)d_in[1];
    const float* x_skip   = (const float*)d_in[3];
    const float* pos_skip = (const float*)d_in[4];
    const float* w1  = (const float*)d_in[6];
    const float* b1  = (const float*)d_in[7];
    const float* g1  = (const float*)d_in[8];
    const float* be1 = (const float*)d_in[9];
    const float* m1  = (const float*)d_in[10];
    const float* v1  = (const float*)d_in[11];
    const float* w2  = (const float*)d_in[12];
    const float* b2  = (const float*)d_in[13];
    const float* g2  = (const float*)d_in[14];
    const float* be2 = (const float*)d_in[15];
    const float* m2  = (const float*)d_in[16];
    const float* v2  = (const float*)d_in[17];

    float* out = (float*)d_out;

    unsigned short* A1hi = (unsigned short*)d_out;
    unsigned short* A1lo = A1hi + (size_t)M_ROWS * K1;
    unsigned short* W1hi = A1lo + (size_t)M_ROWS * K1;
    unsigned short* W1lo = W1hi + (size_t)512 * K1;
    unsigned short* W2hi = (unsigned short*)(out + H_ELEMS);
    unsigned short* W2lo = W2hi + (size_t)512 * 512;
    unsigned short* h1hi = (unsigned short*)d_ws;
    unsigned short* h1lo = h1hi + H_ELEMS;

    // 1) producers
    knn_interp_kernel<<<NB * (NF / QB), 256, 0, stream>>>(x, pos, pos_skip, A1hi, A1lo);
    conv_skip_kernel<<<M_ROWS * 32 / 256, 256, 0, stream>>>(x_skip, A1hi, A1lo);
    conv_w_kernel<<<(K1 * 512 + 255) / 256, 256, 0, stream>>>(w1, W1hi, W1lo, K1);
    conv_w_kernel<<<(512 * 512 + 255) / 256, 256, 0, stream>>>(w2, W2hi, W2lo, 512);

    // 2) Layer 1: [65536 x 384] @ [384 x 512] -> split h1 planes
    gemm_bf3s<true><<<dim3(4 * (M_ROWS / 128)), 256, 0, stream>>>(
        A1hi, A1lo, W1hi, W1lo, K1, b1, g1, be1, m1, v1,
        nullptr, h1hi, h1lo);

    // 3) Layer 2: [65536 x 512] @ [512 x 512] -> f32 out
    gemm_bf3s<false><<<dim3(4 * (M_ROWS / 128)), 256, 0, stream>>>(
        h1hi, h1lo, W2hi, W2lo, HW_, b2, g2, be2, m2, v2,
        out, nullptr, nullptr);

    // 4) tail
    const long long tail = (long long)out_size - (long long)H_ELEMS;
    if (tail > 0) {
        const int mode = (tail - POS_ELEMS >= 2 * M_ROWS) ? 1 : 0;
        tail_kernel<<<(POS_ELEMS + M_ROWS + 255) / 256, 256, 0, stream>>>(
            pos_skip, out + H_ELEMS, mode);
    }
    (void)in_sizes; (void)n_in; (void)ws_size; (void)d_in;
}

// Round 8
// 414.639 us; speedup vs baseline: 1.2367x; 1.2367x over previous
//
#include <hip/hip_runtime.h>
#include <hip/hip_bf16.h>
#include <cstddef>
#include <cstdint>

// Problem constants
#define NB 16
#define NC 1024
#define NF 4096
#define CIN 256
#define CSKIP 128
#define HW_ 512
#define K1 (CIN + CSKIP)                  // 384
#define M_ROWS (NB * NF)                  // 65536
#define H_ELEMS ((size_t)M_ROWS * HW_)    // 33554432
#define POS_ELEMS (M_ROWS * 3)            // 196608

#define QB 64      // queries per kNN block
#define PARTS 4    // candidate quarters per query

typedef __attribute__((ext_vector_type(8))) short bf16x8;
typedef __attribute__((ext_vector_type(4))) float f32x4;
typedef __attribute__((ext_vector_type(4))) unsigned int u32x4;

__device__ __forceinline__ unsigned short f2bf(float f) {
    union { __hip_bfloat16 h; unsigned short u; } cv;
    cv.h = __float2bfloat16(f);
    return cv.u;
}
__device__ __forceinline__ float bf2f(unsigned short u) {
    union { __hip_bfloat16 h; unsigned short u; } cv;
    cv.u = u;
    return __bfloat162float(cv.h);
}
__device__ __forceinline__ void split2(float v, unsigned short& hi, unsigned short& lo) {
    hi = f2bf(v);
    lo = f2bf(v - bf2f(hi));
}

#define GLOAD_LDS(gsrc, ldst)                                                            \
    __builtin_amdgcn_global_load_lds((const __attribute__((address_space(1))) void*)(gsrc), \
                                     (__attribute__((address_space(3))) void*)(ldst), 16, 0, 0)

// ---------------------------------------------------------------------------
// Kernel 1: kNN (K=3) + inverse-distance interpolation (unchanged).
// ---------------------------------------------------------------------------
__launch_bounds__(256)
__global__ void knn_interp_kernel(const float* __restrict__ x,
                                  const float* __restrict__ pos,
                                  const float* __restrict__ pos_skip,
                                  unsigned short* __restrict__ Ahi,
                                  unsigned short* __restrict__ Alo)
{
    __shared__ float4 sp4[NC];
    __shared__ float  s_b[QB * PARTS * 3];
    __shared__ int    s_i[QB * PARTS * 3];
    __shared__ int    s_idx[QB * 3];
    __shared__ float  s_w[QB * 3];

    const int tid   = threadIdx.x;
    const int cloud = blockIdx.x >> 6;
    const int chunk = blockIdx.x & 63;

    const float* pbase = pos + (size_t)cloud * NC * 3;
    for (int j = tid; j < NC; j += 256) {
        const float px = pbase[3 * j + 0];
        const float py = pbase[3 * j + 1];
        const float pz = pbase[3 * j + 2];
        sp4[j] = make_float4(px, py, pz, px * px + py * py + pz * pz);
    }
    __syncthreads();

    const int q    = tid & (QB - 1);
    const int part = tid >> 6;
    const float* qp = pos_skip + ((size_t)cloud * NF + chunk * QB + q) * 3;
    const float qx = qp[0], qy = qp[1], qz = qp[2];
    const float ax = -2.f * qx, ay = -2.f * qy, az = -2.f * qz;
    const float qq = qx * qx + qy * qy + qz * qz;

    float b0 = 1e30f, b1 = 1e30f, b2 = 1e30f;
    int   i0 = 0,     i1 = 0,     i2 = 0;
    const int jbase = part * (NC / PARTS);
#pragma unroll 4
    for (int jj = 0; jj < NC / PARTS; ++jj) {
        const int j = jbase + jj;
        const float4 p = sp4[j];
        const float d = fmaf(ax, p.x, fmaf(ay, p.y, fmaf(az, p.z, p.w))) + qq;
        const bool c0 = d < b0, c1 = d < b1, c2 = d < b2;
        const float nb0 = fminf(b0, d);
        const float nb1 = __builtin_amdgcn_fmed3f(b0, b1, d);
        const float nb2 = __builtin_amdgcn_fmed3f(b1, b2, d);
        const int ni0 = c0 ? j : i0;
        const int ni1 = c0 ? i0 : (c1 ? j : i1);
        const int ni2 = c1 ? i1 : (c2 ? j : i2);
        b0 = nb0; b1 = nb1; b2 = nb2;
        i0 = ni0; i1 = ni1; i2 = ni2;
    }
    {
        const int pb = (q * PARTS + part) * 3;
        s_b[pb + 0] = b0; s_b[pb + 1] = b1; s_b[pb + 2] = b2;
        s_i[pb + 0] = i0; s_i[pb + 1] = i1; s_i[pb + 2] = i2;
    }
    __syncthreads();

    if (tid < QB) {
        const int base = tid * PARTS * 3;
        float m0 = s_b[base + 0], m1 = s_b[base + 1], m2 = s_b[base + 2];
        int   a0 = s_i[base + 0], a1 = s_i[base + 1], a2 = s_i[base + 2];
#pragma unroll
        for (int p = 1; p < PARTS; ++p) {
#pragma unroll
            for (int s = 0; s < 3; ++s) {
                const float d = s_b[base + p * 3 + s];
                const int   j = s_i[base + p * 3 + s];
                const bool c0 = d < m0, c1 = d < m1, c2 = d < m2;
                const float n0 = fminf(m0, d);
                const float n1 = __builtin_amdgcn_fmed3f(m0, m1, d);
                const float n2 = __builtin_amdgcn_fmed3f(m1, m2, d);
                const int e0 = c0 ? j : a0;
                const int e1 = c0 ? a0 : (c1 ? j : a1);
                const int e2 = c1 ? a1 : (c2 ? j : a2);
                m0 = n0; m1 = n1; m2 = n2;
                a0 = e0; a1 = e1; a2 = e2;
            }
        }
        const int id[3] = {a0, a1, a2};
        float w[3], tw = 0.f;
#pragma unroll
        for (int s = 0; s < 3; ++s) {
            const float4 p = sp4[id[s]];
            const float dx = qx - p.x, dy = qy - p.y, dz = qz - p.z;
            const float d2 = fmaf(dx, dx, fmaf(dy, dy, dz * dz));
            w[s] = 1.f / fmaxf(d2, 1e-16f);
            tw += w[s];
        }
        const float winv = 1.f / tw;
#pragma unroll
        for (int s = 0; s < 3; ++s) {
            s_idx[tid * 3 + s] = id[s];
            s_w[tid * 3 + s]   = w[s] * winv;
        }
    }
    __syncthreads();

    const int wave = tid >> 6, lane = tid & 63;
    const float* xc = x + (size_t)cloud * NC * CIN;
    const size_t rowbase = (size_t)cloud * NF + chunk * QB;
    for (int qq2 = wave; qq2 < QB; qq2 += 4) {
        const int   j0 = s_idx[qq2 * 3 + 0], j1 = s_idx[qq2 * 3 + 1], j2 = s_idx[qq2 * 3 + 2];
        const float u0 = s_w[qq2 * 3 + 0],   u1 = s_w[qq2 * 3 + 1],   u2 = s_w[qq2 * 3 + 2];
        const float4 f0 = ((const float4*)(xc + (size_t)j0 * CIN))[lane];
        const float4 f1 = ((const float4*)(xc + (size_t)j1 * CIN))[lane];
        const float4 f2 = ((const float4*)(xc + (size_t)j2 * CIN))[lane];
        float o[4];
        o[0] = u0 * f0.x + u1 * f1.x + u2 * f2.x;
        o[1] = u0 * f0.y + u1 * f1.y + u2 * f2.y;
        o[2] = u0 * f0.z + u1 * f1.z + u2 * f2.z;
        o[3] = u0 * f0.w + u1 * f1.w + u2 * f2.w;
        unsigned short h[4], l[4];
#pragma unroll
        for (int c = 0; c < 4; ++c) split2(o[c], h[c], l[c]);
        uint2 hv, lv;
        hv.x = (unsigned)h[0] | ((unsigned)h[1] << 16);
        hv.y = (unsigned)h[2] | ((unsigned)h[3] << 16);
        lv.x = (unsigned)l[0] | ((unsigned)l[1] << 16);
        lv.y = (unsigned)l[2] | ((unsigned)l[3] << 16);
        const size_t ro = (rowbase + qq2) * K1;
        ((uint2*)(Ahi + ro))[lane] = hv;
        ((uint2*)(Alo + ro))[lane] = lv;
    }
}

// ---------------------------------------------------------------------------
// Kernel 2: x_skip -> split planes at columns 256..383 of A1.
// ---------------------------------------------------------------------------
__launch_bounds__(256)
__global__ void conv_skip_kernel(const float* __restrict__ xs,
                                 unsigned short* __restrict__ Ahi,
                                 unsigned short* __restrict__ Alo)
{
    const int idx = blockIdx.x * 256 + threadIdx.x;
    const int row = idx >> 5;
    const int c4  = idx & 31;
    const float4 v = ((const float4*)(xs + (size_t)row * CSKIP))[c4];
    const float o[4] = {v.x, v.y, v.z, v.w};
    unsigned short h[4], l[4];
#pragma unroll
    for (int c = 0; c < 4; ++c) split2(o[c], h[c], l[c]);
    uint2 hv, lv;
    hv.x = (unsigned)h[0] | ((unsigned)h[1] << 16);
    hv.y = (unsigned)h[2] | ((unsigned)h[3] << 16);
    lv.x = (unsigned)l[0] | ((unsigned)l[1] << 16);
    lv.y = (unsigned)l[2] | ((unsigned)l[3] << 16);
    const size_t off = (size_t)row * K1 + CIN + c4 * 4;
    *(uint2*)(Ahi + off) = hv;
    *(uint2*)(Alo + off) = lv;
}

// ---------------------------------------------------------------------------
// Kernel 3: weight transpose + split -> WT planes [512][Kd].
// ---------------------------------------------------------------------------
__launch_bounds__(256)
__global__ void conv_w_kernel(const float* __restrict__ w,
                              unsigned short* __restrict__ WhiT,
                              unsigned short* __restrict__ WloT, int Kd)
{
    const int idx = blockIdx.x * 256 + threadIdx.x;
    if (idx >= Kd * 512) return;
    const int k = idx >> 9;
    const int n = idx & 511;
    const float v = w[(size_t)k * 512 + n];
    unsigned short h, l;
    split2(v, h, l);
    WhiT[(size_t)n * Kd + k] = h;
    WloT[(size_t)n * Kd + k] = l;
}

// ---------------------------------------------------------------------------
// Kernel 4 (v4): v2 compute structure (A and W both in LDS) + counted-vmcnt
// deep pipeline: A 3-deep (48KB), W 2-deep (32KB), one raw s_barrier/tile,
// s_waitcnt vmcnt(4) retires exactly {A(t), W(t)} per the in-order vmem
// queue [A0,W0,A1 | W1,A2 | W2,A3 | ...]. Never drains the prefetch.
// Epilogue: acc -> packed-u32 LDS C-tile -> coalesced global stores.
// ---------------------------------------------------------------------------
#define A_BUF_BYTES 16384                 // hi 8KB + lo 8KB
#define W_BASE      49152                 // 3 * A_BUF_BYTES
#define SMEM_BYTES  81920                 // 48KB A + 32KB W

__device__ __forceinline__ int cswz(int row) {
    return (((row >> 2) & 3) << 2) ^ (((row >> 3) & 1) << 1) ^ ((row >> 4) & 1);
}

template <bool SPLIT_OUT>
__launch_bounds__(256, 2)
__global__ void gemm_bf3s(const unsigned short* __restrict__ Ahi,
                          const unsigned short* __restrict__ Alo,
                          const unsigned short* __restrict__ Whi,   // [512][K]
                          const unsigned short* __restrict__ Wlo,
                          int K,
                          const float* __restrict__ bias,
                          const float* __restrict__ gamma,
                          const float* __restrict__ beta,
                          const float* __restrict__ mean,
                          const float* __restrict__ var,
                          float* __restrict__ Cf,
                          unsigned short* __restrict__ Chi,
                          unsigned short* __restrict__ Clo)
{
    __shared__ alignas(16) unsigned char smem[SMEM_BYTES];

    // XCD swizzle: 4 N-blocks of an M-panel land consecutively on one XCD.
    const int bid  = blockIdx.x;
    const int xcd  = bid & 7;
    const int slot = bid >> 3;
    const int bx   = slot & 3;
    const int by   = xcd + (slot >> 2) * 8;
    const int bm   = by * 128;
    const int bn   = bx * 128;

    const int tid  = threadIdx.x;
    const int lane = tid & 63;
    const int wv   = tid >> 6;
    const int wr   = wv >> 1;
    const int wc   = wv & 1;

    const int sr  = lane >> 2;      // staging row within 16-row chunk
    const int sgp = lane & 3;       // staging physical granule

    f32x4 acc[4][4];
#pragma unroll
    for (int i = 0; i < 4; ++i)
#pragma unroll
        for (int j = 0; j < 4; ++j) acc[i][j] = (f32x4){0.f, 0.f, 0.f, 0.f};

    // A-tile (hi+lo) -> A-buffer ab in [0,3): 4 gload_lds per thread
    auto stageA = [&](int ab, int kk) {
#pragma unroll
        for (int i = 0; i < 2; ++i) {
            const int rl = (wv * 2 + i) * 16 + sr;
            const int g  = sgp ^ ((rl >> 1) & 3);
            const unsigned dst = ab * A_BUF_BYTES + (wv * 2 + i) * 1024;
            const size_t ro = (size_t)(bm + rl) * K + kk + g * 8;
            GLOAD_LDS(Ahi + ro, smem + dst);
            GLOAD_LDS(Alo + ro, smem + 8192 + dst);
        }
    };
    // W-tile (hi+lo) -> W-buffer wb in [0,2): 4 gload_lds per thread
    auto stageW = [&](int wb, int kk) {
#pragma unroll
        for (int i = 0; i < 2; ++i) {
            const int rl = (wv * 2 + i) * 16 + sr;
            const int g  = sgp ^ ((rl >> 1) & 3);
            const unsigned dst = W_BASE + wb * A_BUF_BYTES + (wv * 2 + i) * 1024;
            const size_t ro = (size_t)(bn + rl) * K + kk + g * 8;
            GLOAD_LDS(Whi + ro, smem + dst);
            GLOAD_LDS(Wlo + ro, smem + 8192 + dst);
        }
    };

    auto compute = [&](int ab, int wb) {
        const unsigned short* sAh = (const unsigned short*)(smem + ab * A_BUF_BYTES);
        const unsigned short* sAl = (const unsigned short*)(smem + ab * A_BUF_BYTES + 8192);
        const unsigned short* sWh = (const unsigned short*)(smem + W_BASE + wb * A_BUF_BYTES);
        const unsigned short* sWl = (const unsigned short*)(smem + W_BASE + wb * A_BUF_BYTES + 8192);
        bf16x8 ah[4], al[4], wh[4], wl[4];
#pragma unroll
        for (int i = 0; i < 4; ++i) {
            const int r  = wr * 64 + i * 16 + (lane & 15);
            const int ga = (lane >> 4) ^ ((r >> 1) & 3);
            ah[i] = *(const bf16x8*)(sAh + r * 32 + ga * 8);
            al[i] = *(const bf16x8*)(sAl + r * 32 + ga * 8);
            const int c  = wc * 64 + i * 16 + (lane & 15);
            const int gb = (lane >> 4) ^ ((c >> 1) & 3);
            wh[i] = *(const bf16x8*)(sWh + c * 32 + gb * 8);
            wl[i] = *(const bf16x8*)(sWl + c * 32 + gb * 8);
        }
#pragma unroll
        for (int i = 0; i < 4; ++i)
#pragma unroll
            for (int j = 0; j < 4; ++j)
                acc[i][j] = __builtin_amdgcn_mfma_f32_16x16x32_bf16(ah[i], wh[j], acc[i][j], 0, 0, 0);
#pragma unroll
        for (int i = 0; i < 4; ++i)
#pragma unroll
            for (int j = 0; j < 4; ++j)
                acc[i][j] = __builtin_amdgcn_mfma_f32_16x16x32_bf16(ah[i], wl[j], acc[i][j], 0, 0, 0);
#pragma unroll
        for (int i = 0; i < 4; ++i)
#pragma unroll
            for (int j = 0; j < 4; ++j)
                acc[i][j] = __builtin_amdgcn_mfma_f32_16x16x32_bf16(al[i], wh[j], acc[i][j], 0, 0, 0);
    };

    const int NT = K / 32;                       // 12 or 16 (>= 3)
    // prologue queue: A(0), W(0), A(1)  -> vmcnt(4) at iter 0 retires A0,W0
    stageA(0, 0);
    stageW(0, 0);
    stageA(1, 32);
    int ab = 0;                                  // A-buffer of tile t
    for (int t = 0; t < NT; ++t) {
        if (t + 1 < NT) asm volatile("s_waitcnt vmcnt(4)" ::: "memory");
        else            asm volatile("s_waitcnt vmcnt(0)" ::: "memory");
        __builtin_amdgcn_s_barrier();            // raw: no implicit vmcnt drain
        asm volatile("" ::: "memory");           // fence: no ds_read hoist above barrier
        const int wb = t & 1;
        if (t + 1 < NT) stageW(wb ^ 1, (t + 1) * 32);
        if (t + 2 < NT) {
            int a2 = ab + 2; if (a2 >= 3) a2 -= 3;
            stageA(a2, (t + 2) * 32);
        }
        compute(ab, wb);
        ++ab; if (ab == 3) ab = 0;
    }

    // ---- epilogue: BN -> packed u32 LDS C-tile -> coalesced global stores
    __syncthreads();                            // vmcnt already 0; waves aligned
    unsigned int* sC = (unsigned int*)smem;     // [128][128] u32 (64KB)

    const int lc  = lane & 15;
    const int lr4 = (lane >> 4) * 4;
#pragma unroll
    for (int j = 0; j < 4; ++j) {
        const int col  = wc * 64 + j * 16 + lc;            // tile-local col
        const int colg = bn + col;
        const float s  = gamma[colg] / sqrtf(var[colg] + 1e-5f);
        const float sh = beta[colg] - mean[colg] * s;
        const float bb = bias[colg];
        const int g    = col >> 2;
#pragma unroll
        for (int i = 0; i < 4; ++i) {
            const f32x4 v = acc[i][j];
#pragma unroll
            for (int q = 0; q < 4; ++q) {
                const int row = wr * 64 + i * 16 + lr4 + q;
                const float val = fmaxf(v[q] + bb, 0.f) * s + sh;
                unsigned u;
                if (SPLIT_OUT) {
                    unsigned short h, l;
                    split2(val, h, l);
                    u = (unsigned)h | ((unsigned)l << 16);
                } else {
                    u = __float_as_uint(val);
                }
                sC[row * 128 + ((g ^ cswz(row)) << 2) + (col & 3)] = u;
            }
        }
    }
    __syncthreads();

    // reader: per iter, 2 rows x 32 granules -> 256B contiguous per row-plane
#pragma unroll
    for (int it = 0; it < 16; ++it) {
        const int row = wv * 32 + it * 2 + (lane >> 5);
        const int g   = lane & 31;
        const u32x4 v = *(const u32x4*)(sC + row * 128 + ((g ^ cswz(row)) << 2));
        const size_t rg = (size_t)(bm + row) * HW_ + bn + g * 4;
        if (SPLIT_OUT) {
            uint2 hv, lv;
            hv.x = (v[0] & 0xffffu) | (v[1] << 16);
            hv.y = (v[2] & 0xffffu) | (v[3] << 16);
            lv.x = (v[0] >> 16) | (v[1] & 0xffff0000u);
            lv.y = (v[2] >> 16) | (v[3] & 0xffff0000u);
            *(uint2*)(Chi + rg) = hv;
            *(uint2*)(Clo + rg) = lv;
        } else {
            *(u32x4*)((unsigned int*)Cf + rg) = v;
        }
    }
}

// ---------------------------------------------------------------------------
// Kernel 5: tail outputs (runs LAST; reclaims W2^T scratch in the tail region).
// ---------------------------------------------------------------------------
__launch_bounds__(256)
__global__ void tail_kernel(const float* __restrict__ pos_skip,
                            float* __restrict__ outp, int mode)
{
    const int i = blockIdx.x * 256 + threadIdx.x;
    if (i < POS_ELEMS) outp[i] = pos_skip[i];
    const int bi = i - POS_ELEMS;
    if (bi >= 0 && bi < M_ROWS) {
        if (mode == 0) {
            outp[POS_ELEMS + bi] = (float)(bi >> 12);
        } else {
            ((unsigned long long*)(outp + POS_ELEMS))[bi] = (unsigned long long)(bi >> 12);
        }
    }
}

// ---------------------------------------------------------------------------
extern "C" void kernel_launch(void* const* d_in, const int* in_sizes, int n_in,
                              void* d_out, int out_size, void* d_ws, size_t ws_size,
                              hipStream_t stream)
{
    const float* x        = (const float*)d_in[0];
    const float* pos      = (const float*)d_in[1];
    const float* x_skip   = (const float*)d_in[3];
    const float* pos_skip = (const float*)d_in[4];
    const float* w1  = (const float*)d_in[6];
    const float* b1  = (const float*)d_in[7];
    const float* g1  = (const float*)d_in[8];
    const float* be1 = (const float*)d_in[9];
    const float* m1  = (const float*)d_in[10];
    const float* v1  = (const float*)d_in[11];
    const float* w2  = (const float*)d_in[12];
    const float* b2  = (const float*)d_in[13];
    const float* g2  = (const float*)d_in[14];
    const float* be2 = (const float*)d_in[15];
    const float* m2  = (const float*)d_in[16];
    const float* v2  = (const float*)d_in[17];

    float* out = (float*)d_out;

    unsigned short* A1hi = (unsigned short*)d_out;
    unsigned short* A1lo = A1hi + (size_t)M_ROWS * K1;
    unsigned short* W1hi = A1lo + (size_t)M_ROWS * K1;
    unsigned short* W1lo = W1hi + (size_t)512 * K1;
    unsigned short* W2hi = (unsigned short*)(out + H_ELEMS);
    unsigned short* W2lo = W2hi + (size_t)512 * 512;
    unsigned short* h1hi = (unsigned short*)d_ws;
    unsigned short* h1lo = h1hi + H_ELEMS;

    // 1) producers
    knn_interp_kernel<<<NB * (NF / QB), 256, 0, stream>>>(x, pos, pos_skip, A1hi, A1lo);
    conv_skip_kernel<<<M_ROWS * 32 / 256, 256, 0, stream>>>(x_skip, A1hi, A1lo);
    conv_w_kernel<<<(K1 * 512 + 255) / 256, 256, 0, stream>>>(w1, W1hi, W1lo, K1);
    conv_w_kernel<<<(512 * 512 + 255) / 256, 256, 0, stream>>>(w2, W2hi, W2lo, 512);

    // 2) Layer 1: [65536 x 384] @ [384 x 512] -> split h1 planes
    gemm_bf3s<true><<<dim3(4 * (M_ROWS / 128)), 256, 0, stream>>>(
        A1hi, A1lo, W1hi, W1lo, K1, b1, g1, be1, m1, v1,
        nullptr, h1hi, h1lo);

    // 3) Layer 2: [65536 x 512] @ [512 x 512] -> f32 out
    gemm_bf3s<false><<<dim3(4 * (M_ROWS / 128)), 256, 0, stream>>>(
        h1hi, h1lo, W2hi, W2lo, HW_, b2, g2, be2, m2, v2,
        out, nullptr, nullptr);

    // 4) tail
    const long long tail = (long long)out_size - (long long)H_ELEMS;
    if (tail > 0) {
        const int mode = (tail - POS_ELEMS >= 2 * M_ROWS) ? 1 : 0;
        tail_kernel<<<(POS_ELEMS + M_ROWS + 255) / 256, 256, 0, stream>>>(
            pos_skip, out + H_ELEMS, mode);
    }
    (void)in_sizes; (void)n_in; (void)ws_size; (void)d_in;
}

// Round 9
// 389.192 us; speedup vs baseline: 1.3175x; 1.0654x over previous
//
#include <hip/hip_runtime.h>
#include <hip/hip_bf16.h>
#include <hip/hip_fp16.h>
#include <cstddef>
#include <cstdint>

// Problem constants
#define NB 16
#define NC 1024
#define NF 4096
#define CIN 256
#define CSKIP 128
#define HW_ 512
#define K1 (CIN + CSKIP)                  // 384
#define M_ROWS (NB * NF)                  // 65536
#define H_ELEMS ((size_t)M_ROWS * HW_)    // 33554432
#define POS_ELEMS (M_ROWS * 3)            // 196608

#define QB 64      // queries per kNN block
#define PARTS 4    // candidate quarters per query

typedef __attribute__((ext_vector_type(8))) _Float16 f16x8;
typedef __attribute__((ext_vector_type(4))) float f32x4;
typedef __attribute__((ext_vector_type(4))) unsigned int u32x4;

// split v into f16 hi + f16 lo (lo = remainder). 2-pass GEMM keeps
// Ahi*Whi + Alo*Whi; dropped Ahi*Wlo term ~ sqrt(K)*2^-11*|a||w| ~ 3e-4.
__device__ __forceinline__ void split2h(float v, unsigned short& hi, unsigned short& lo) {
    union { _Float16 f; unsigned short u; } ch, cl;
    ch.f = (_Float16)v;
    cl.f = (_Float16)(v - (float)ch.f);
    hi = ch.u; lo = cl.u;
}

#define GLOAD_LDS(gsrc, ldst)                                                            \
    __builtin_amdgcn_global_load_lds((const __attribute__((address_space(1))) void*)(gsrc), \
                                     (__attribute__((address_space(3))) void*)(ldst), 16, 0, 0)

// ---------------------------------------------------------------------------
// Kernel 1: kNN (K=3) + inverse-distance interpolation -> f16 split planes.
// ---------------------------------------------------------------------------
__launch_bounds__(256)
__global__ void knn_interp_kernel(const float* __restrict__ x,
                                  const float* __restrict__ pos,
                                  const float* __restrict__ pos_skip,
                                  unsigned short* __restrict__ Ahi,
                                  unsigned short* __restrict__ Alo)
{
    __shared__ float4 sp4[NC];
    __shared__ float  s_b[QB * PARTS * 3];
    __shared__ int    s_i[QB * PARTS * 3];
    __shared__ int    s_idx[QB * 3];
    __shared__ float  s_w[QB * 3];

    const int tid   = threadIdx.x;
    const int cloud = blockIdx.x >> 6;
    const int chunk = blockIdx.x & 63;

    const float* pbase = pos + (size_t)cloud * NC * 3;
    for (int j = tid; j < NC; j += 256) {
        const float px = pbase[3 * j + 0];
        const float py = pbase[3 * j + 1];
        const float pz = pbase[3 * j + 2];
        sp4[j] = make_float4(px, py, pz, px * px + py * py + pz * pz);
    }
    __syncthreads();

    const int q    = tid & (QB - 1);
    const int part = tid >> 6;
    const float* qp = pos_skip + ((size_t)cloud * NF + chunk * QB + q) * 3;
    const float qx = qp[0], qy = qp[1], qz = qp[2];
    const float ax = -2.f * qx, ay = -2.f * qy, az = -2.f * qz;
    const float qq = qx * qx + qy * qy + qz * qz;

    float b0 = 1e30f, b1 = 1e30f, b2 = 1e30f;
    int   i0 = 0,     i1 = 0,     i2 = 0;
    const int jbase = part * (NC / PARTS);
#pragma unroll 4
    for (int jj = 0; jj < NC / PARTS; ++jj) {
        const int j = jbase + jj;
        const float4 p = sp4[j];
        const float d = fmaf(ax, p.x, fmaf(ay, p.y, fmaf(az, p.z, p.w))) + qq;
        const bool c0 = d < b0, c1 = d < b1, c2 = d < b2;
        const float nb0 = fminf(b0, d);
        const float nb1 = __builtin_amdgcn_fmed3f(b0, b1, d);
        const float nb2 = __builtin_amdgcn_fmed3f(b1, b2, d);
        const int ni0 = c0 ? j : i0;
        const int ni1 = c0 ? i0 : (c1 ? j : i1);
        const int ni2 = c1 ? i1 : (c2 ? j : i2);
        b0 = nb0; b1 = nb1; b2 = nb2;
        i0 = ni0; i1 = ni1; i2 = ni2;
    }
    {
        const int pb = (q * PARTS + part) * 3;
        s_b[pb + 0] = b0; s_b[pb + 1] = b1; s_b[pb + 2] = b2;
        s_i[pb + 0] = i0; s_i[pb + 1] = i1; s_i[pb + 2] = i2;
    }
    __syncthreads();

    if (tid < QB) {
        const int base = tid * PARTS * 3;
        float m0 = s_b[base + 0], m1 = s_b[base + 1], m2 = s_b[base + 2];
        int   a0 = s_i[base + 0], a1 = s_i[base + 1], a2 = s_i[base + 2];
#pragma unroll
        for (int p = 1; p < PARTS; ++p) {
#pragma unroll
            for (int s = 0; s < 3; ++s) {
                const float d = s_b[base + p * 3 + s];
                const int   j = s_i[base + p * 3 + s];
                const bool c0 = d < m0, c1 = d < m1, c2 = d < m2;
                const float n0 = fminf(m0, d);
                const float n1 = __builtin_amdgcn_fmed3f(m0, m1, d);
                const float n2 = __builtin_amdgcn_fmed3f(m1, m2, d);
                const int e0 = c0 ? j : a0;
                const int e1 = c0 ? a0 : (c1 ? j : a1);
                const int e2 = c1 ? a1 : (c2 ? j : a2);
                m0 = n0; m1 = n1; m2 = n2;
                a0 = e0; a1 = e1; a2 = e2;
            }
        }
        const int id[3] = {a0, a1, a2};
        float w[3], tw = 0.f;
#pragma unroll
        for (int s = 0; s < 3; ++s) {
            const float4 p = sp4[id[s]];
            const float dx = qx - p.x, dy = qy - p.y, dz = qz - p.z;
            const float d2 = fmaf(dx, dx, fmaf(dy, dy, dz * dz));
            w[s] = 1.f / fmaxf(d2, 1e-16f);
            tw += w[s];
        }
        const float winv = 1.f / tw;
#pragma unroll
        for (int s = 0; s < 3; ++s) {
            s_idx[tid * 3 + s] = id[s];
            s_w[tid * 3 + s]   = w[s] * winv;
        }
    }
    __syncthreads();

    const int wave = tid >> 6, lane = tid & 63;
    const float* xc = x + (size_t)cloud * NC * CIN;
    const size_t rowbase = (size_t)cloud * NF + chunk * QB;
    for (int qq2 = wave; qq2 < QB; qq2 += 4) {
        const int   j0 = s_idx[qq2 * 3 + 0], j1 = s_idx[qq2 * 3 + 1], j2 = s_idx[qq2 * 3 + 2];
        const float u0 = s_w[qq2 * 3 + 0],   u1 = s_w[qq2 * 3 + 1],   u2 = s_w[qq2 * 3 + 2];
        const float4 f0 = ((const float4*)(xc + (size_t)j0 * CIN))[lane];
        const float4 f1 = ((const float4*)(xc + (size_t)j1 * CIN))[lane];
        const float4 f2 = ((const float4*)(xc + (size_t)j2 * CIN))[lane];
        float o[4];
        o[0] = u0 * f0.x + u1 * f1.x + u2 * f2.x;
        o[1] = u0 * f0.y + u1 * f1.y + u2 * f2.y;
        o[2] = u0 * f0.z + u1 * f1.z + u2 * f2.z;
        o[3] = u0 * f0.w + u1 * f1.w + u2 * f2.w;
        unsigned short h[4], l[4];
#pragma unroll
        for (int c = 0; c < 4; ++c) split2h(o[c], h[c], l[c]);
        uint2 hv, lv;
        hv.x = (unsigned)h[0] | ((unsigned)h[1] << 16);
        hv.y = (unsigned)h[2] | ((unsigned)h[3] << 16);
        lv.x = (unsigned)l[0] | ((unsigned)l[1] << 16);
        lv.y = (unsigned)l[2] | ((unsigned)l[3] << 16);
        const size_t ro = (rowbase + qq2) * K1;
        ((uint2*)(Ahi + ro))[lane] = hv;
        ((uint2*)(Alo + ro))[lane] = lv;
    }
}

// ---------------------------------------------------------------------------
// Kernel 2: x_skip -> f16 split planes at columns 256..383 of A1.
// ---------------------------------------------------------------------------
__launch_bounds__(256)
__global__ void conv_skip_kernel(const float* __restrict__ xs,
                                 unsigned short* __restrict__ Ahi,
                                 unsigned short* __restrict__ Alo)
{
    const int idx = blockIdx.x * 256 + threadIdx.x;
    const int row = idx >> 5;
    const int c4  = idx & 31;
    const float4 v = ((const float4*)(xs + (size_t)row * CSKIP))[c4];
    const float o[4] = {v.x, v.y, v.z, v.w};
    unsigned short h[4], l[4];
#pragma unroll
    for (int c = 0; c < 4; ++c) split2h(o[c], h[c], l[c]);
    uint2 hv, lv;
    hv.x = (unsigned)h[0] | ((unsigned)h[1] << 16);
    hv.y = (unsigned)h[2] | ((unsigned)h[3] << 16);
    lv.x = (unsigned)l[0] | ((unsigned)l[1] << 16);
    lv.y = (unsigned)l[2] | ((unsigned)l[3] << 16);
    const size_t off = (size_t)row * K1 + CIN + c4 * 4;
    *(uint2*)(Ahi + off) = hv;
    *(uint2*)(Alo + off) = lv;
}

// ---------------------------------------------------------------------------
// Kernel 3: weight transpose: w [Kd][512] f32 -> W^T hi plane [512][Kd] f16.
// (lo plane no longer needed: 2-pass drops the Ahi*Wlo term.)
// ---------------------------------------------------------------------------
__launch_bounds__(256)
__global__ void conv_w_kernel(const float* __restrict__ w,
                              unsigned short* __restrict__ WhiT, int Kd)
{
    const int idx = blockIdx.x * 256 + threadIdx.x;
    if (idx >= Kd * 512) return;
    const int k = idx >> 9;
    const int n = idx & 511;
    union { _Float16 f; unsigned short u; } ch;
    ch.f = (_Float16)w[(size_t)k * 512 + n];
    WhiT[(size_t)n * Kd + k] = ch.u;
}

// ---------------------------------------------------------------------------
// Kernel 4 (v5): f16 2-pass split NT-GEMM on the validated v4 pipeline.
// A (hi/lo) 3-deep in LDS (48KB), W (hi only) 2-deep (16KB); counted
// s_waitcnt vmcnt(4) + one raw s_barrier per tile. Per 32-K tile:
// 12 ds_read_b128, 32 MFMA (hh + lh). Epilogue: packed-u32 LDS C-tile.
// ---------------------------------------------------------------------------
#define A_BUF_BYTES 16384                 // hi 8KB + lo 8KB
#define W_BASE      49152                 // 3 * A_BUF_BYTES
#define SMEM_BYTES  65536                 // 48KB A + 16KB W; epilogue reuses 64KB

__device__ __forceinline__ int cswz(int row) {
    return (((row >> 2) & 3) << 2) ^ (((row >> 3) & 1) << 1) ^ ((row >> 4) & 1);
}

template <bool SPLIT_OUT>
__launch_bounds__(256, 2)
__global__ void gemm_f16_2p(const unsigned short* __restrict__ Ahi,
                            const unsigned short* __restrict__ Alo,
                            const unsigned short* __restrict__ Whi,   // [512][K]
                            int K,
                            const float* __restrict__ bias,
                            const float* __restrict__ gamma,
                            const float* __restrict__ beta,
                            const float* __restrict__ mean,
                            const float* __restrict__ var,
                            float* __restrict__ Cf,
                            unsigned short* __restrict__ Chi,
                            unsigned short* __restrict__ Clo)
{
    __shared__ alignas(16) unsigned char smem[SMEM_BYTES];

    // XCD swizzle: 4 N-blocks of an M-panel land consecutively on one XCD.
    const int bid  = blockIdx.x;
    const int xcd  = bid & 7;
    const int slot = bid >> 3;
    const int bx   = slot & 3;
    const int by   = xcd + (slot >> 2) * 8;
    const int bm   = by * 128;
    const int bn   = bx * 128;

    const int tid  = threadIdx.x;
    const int lane = tid & 63;
    const int wv   = tid >> 6;
    const int wr   = wv >> 1;
    const int wc   = wv & 1;

    const int sr  = lane >> 2;      // staging row within 16-row chunk
    const int sgp = lane & 3;       // staging physical granule

    f32x4 acc[4][4];
#pragma unroll
    for (int i = 0; i < 4; ++i)
#pragma unroll
        for (int j = 0; j < 4; ++j) acc[i][j] = (f32x4){0.f, 0.f, 0.f, 0.f};

    // A-tile (hi+lo) -> A-buffer ab in [0,3): 4 gload_lds per thread
    auto stageA = [&](int ab, int kk) {
#pragma unroll
        for (int i = 0; i < 2; ++i) {
            const int rl = (wv * 2 + i) * 16 + sr;
            const int g  = sgp ^ ((rl >> 1) & 3);
            const unsigned dst = ab * A_BUF_BYTES + (wv * 2 + i) * 1024;
            const size_t ro = (size_t)(bm + rl) * K + kk + g * 8;
            GLOAD_LDS(Ahi + ro, smem + dst);
            GLOAD_LDS(Alo + ro, smem + 8192 + dst);
        }
    };
    // W-tile (hi only) -> W-buffer wb in [0,2): 2 gload_lds per thread
    auto stageW = [&](int wb, int kk) {
#pragma unroll
        for (int i = 0; i < 2; ++i) {
            const int rl = (wv * 2 + i) * 16 + sr;
            const int g  = sgp ^ ((rl >> 1) & 3);
            const unsigned dst = W_BASE + wb * 8192 + (wv * 2 + i) * 1024;
            const size_t ro = (size_t)(bn + rl) * K + kk + g * 8;
            GLOAD_LDS(Whi + ro, smem + dst);
        }
    };

    auto compute = [&](int ab, int wb) {
        const unsigned short* sAh = (const unsigned short*)(smem + ab * A_BUF_BYTES);
        const unsigned short* sAl = (const unsigned short*)(smem + ab * A_BUF_BYTES + 8192);
        const unsigned short* sWh = (const unsigned short*)(smem + W_BASE + wb * 8192);
        f16x8 ah[4], al[4], wh[4];
#pragma unroll
        for (int i = 0; i < 4; ++i) {
            const int r  = wr * 64 + i * 16 + (lane & 15);
            const int ga = (lane >> 4) ^ ((r >> 1) & 3);
            ah[i] = *(const f16x8*)(sAh + r * 32 + ga * 8);
            al[i] = *(const f16x8*)(sAl + r * 32 + ga * 8);
            const int c  = wc * 64 + i * 16 + (lane & 15);
            const int gb = (lane >> 4) ^ ((c >> 1) & 3);
            wh[i] = *(const f16x8*)(sWh + c * 32 + gb * 8);
        }
#pragma unroll
        for (int i = 0; i < 4; ++i)
#pragma unroll
            for (int j = 0; j < 4; ++j)
                acc[i][j] = __builtin_amdgcn_mfma_f32_16x16x32_f16(ah[i], wh[j], acc[i][j], 0, 0, 0);
#pragma unroll
        for (int i = 0; i < 4; ++i)
#pragma unroll
            for (int j = 0; j < 4; ++j)
                acc[i][j] = __builtin_amdgcn_mfma_f32_16x16x32_f16(al[i], wh[j], acc[i][j], 0, 0, 0);
    };

    const int NT = K / 32;                       // 12 or 16
    // prologue queue: A0(4), W0(2), A1(4) -> vmcnt(4) at iter 0 retires A0,W0
    stageA(0, 0);
    stageW(0, 0);
    stageA(1, 32);
    int ab = 0;
    for (int t = 0; t < NT; ++t) {
        if (t + 1 < NT) asm volatile("s_waitcnt vmcnt(4)" ::: "memory");
        else            asm volatile("s_waitcnt vmcnt(0)" ::: "memory");
        __builtin_amdgcn_s_barrier();            // raw: no implicit vmcnt drain
        asm volatile("" ::: "memory");
        const int wb = t & 1;
        if (t + 1 < NT) stageW(wb ^ 1, (t + 1) * 32);
        if (t + 2 < NT) {
            int a2 = ab + 2; if (a2 >= 3) a2 -= 3;
            stageA(a2, (t + 2) * 32);
        }
        compute(ab, wb);
        ++ab; if (ab == 3) ab = 0;
    }

    // ---- epilogue: BN -> packed u32 LDS C-tile -> coalesced global stores
    __syncthreads();
    unsigned int* sC = (unsigned int*)smem;     // [128][128] u32 (64KB)

    const int lc  = lane & 15;
    const int lr4 = (lane >> 4) * 4;
#pragma unroll
    for (int j = 0; j < 4; ++j) {
        const int col  = wc * 64 + j * 16 + lc;
        const int colg = bn + col;
        const float s  = gamma[colg] / sqrtf(var[colg] + 1e-5f);
        const float sh = beta[colg] - mean[colg] * s;
        const float bb = bias[colg];
        const int g    = col >> 2;
#pragma unroll
        for (int i = 0; i < 4; ++i) {
            const f32x4 v = acc[i][j];
#pragma unroll
            for (int q = 0; q < 4; ++q) {
                const int row = wr * 64 + i * 16 + lr4 + q;
                const float val = fmaxf(v[q] + bb, 0.f) * s + sh;
                unsigned u;
                if (SPLIT_OUT) {
                    unsigned short h, l;
                    split2h(val, h, l);
                    u = (unsigned)h | ((unsigned)l << 16);
                } else {
                    u = __float_as_uint(val);
                }
                sC[row * 128 + ((g ^ cswz(row)) << 2) + (col & 3)] = u;
            }
        }
    }
    __syncthreads();

#pragma unroll
    for (int it = 0; it < 16; ++it) {
        const int row = wv * 32 + it * 2 + (lane >> 5);
        const int g   = lane & 31;
        const u32x4 v = *(const u32x4*)(sC + row * 128 + ((g ^ cswz(row)) << 2));
        const size_t rg = (size_t)(bm + row) * HW_ + bn + g * 4;
        if (SPLIT_OUT) {
            uint2 hv, lv;
            hv.x = (v[0] & 0xffffu) | (v[1] << 16);
            hv.y = (v[2] & 0xffffu) | (v[3] << 16);
            lv.x = (v[0] >> 16) | (v[1] & 0xffff0000u);
            lv.y = (v[2] >> 16) | (v[3] & 0xffff0000u);
            *(uint2*)(Chi + rg) = hv;
            *(uint2*)(Clo + rg) = lv;
        } else {
            *(u32x4*)((unsigned int*)Cf + rg) = v;
        }
    }
}

// ---------------------------------------------------------------------------
// Kernel 5: tail outputs (runs LAST; reclaims W2^T scratch in the tail region).
// ---------------------------------------------------------------------------
__launch_bounds__(256)
__global__ void tail_kernel(const float* __restrict__ pos_skip,
                            float* __restrict__ outp, int mode)
{
    const int i = blockIdx.x * 256 + threadIdx.x;
    if (i < POS_ELEMS) outp[i] = pos_skip[i];
    const int bi = i - POS_ELEMS;
    if (bi >= 0 && bi < M_ROWS) {
        if (mode == 0) {
            outp[POS_ELEMS + bi] = (float)(bi >> 12);
        } else {
            ((unsigned long long*)(outp + POS_ELEMS))[bi] = (unsigned long long)(bi >> 12);
        }
    }
}

// ---------------------------------------------------------------------------
extern "C" void kernel_launch(void* const* d_in, const int* in_sizes, int n_in,
                              void* d_out, int out_size, void* d_ws, size_t ws_size,
                              hipStream_t stream)
{
    const float* x        = (const float*)d_in[0];
    const float* pos      = (const float*)d_in[1];
    const float* x_skip   = (const float*)d_in[3];
    const float* pos_skip = (const float*)d_in[4];
    const float* w1  = (const float*)d_in[6];
    const float* b1  = (const float*)d_in[7];
    const float* g1  = (const float*)d_in[8];
    const float* be1 = (const float*)d_in[9];
    const float* m1  = (const float*)d_in[10];
    const float* v1  = (const float*)d_in[11];
    const float* w2  = (const float*)d_in[12];
    const float* b2  = (const float*)d_in[13];
    const float* g2  = (const float*)d_in[14];
    const float* be2 = (const float*)d_in[15];
    const float* m2  = (const float*)d_in[16];
    const float* v2  = (const float*)d_in[17];

    float* out = (float*)d_out;

    unsigned short* A1hi = (unsigned short*)d_out;
    unsigned short* A1lo = A1hi + (size_t)M_ROWS * K1;
    unsigned short* W1hi = A1lo + (size_t)M_ROWS * K1;
    unsigned short* W2hi = (unsigned short*)(out + H_ELEMS);   // 512KB in tail region
    unsigned short* h1hi = (unsigned short*)d_ws;
    unsigned short* h1lo = h1hi + H_ELEMS;

    // 1) producers
    knn_interp_kernel<<<NB * (NF / QB), 256, 0, stream>>>(x, pos, pos_skip, A1hi, A1lo);
    conv_skip_kernel<<<M_ROWS * 32 / 256, 256, 0, stream>>>(x_skip, A1hi, A1lo);
    conv_w_kernel<<<(K1 * 512 + 255) / 256, 256, 0, stream>>>(w1, W1hi, K1);
    conv_w_kernel<<<(512 * 512 + 255) / 256, 256, 0, stream>>>(w2, W2hi, 512);

    // 2) Layer 1: [65536 x 384] @ [384 x 512] -> split h1 planes (f16)
    gemm_f16_2p<true><<<dim3(4 * (M_ROWS / 128)), 256, 0, stream>>>(
        A1hi, A1lo, W1hi, K1, b1, g1, be1, m1, v1,
        nullptr, h1hi, h1lo);

    // 3) Layer 2: [65536 x 512] @ [512 x 512] -> f32 out
    gemm_f16_2p<false><<<dim3(4 * (M_ROWS / 128)), 256, 0, stream>>>(
        h1hi, h1lo, W2hi, HW_, b2, g2, be2, m2, v2,
        out, nullptr, nullptr);

    // 4) tail
    const long long tail = (long long)out_size - (long long)H_ELEMS;
    if (tail > 0) {
        const int mode = (tail - POS_ELEMS >= 2 * M_ROWS) ? 1 : 0;
        tail_kernel<<<(POS_ELEMS + M_ROWS + 255) / 256, 256, 0, stream>>>(
            pos_skip, out + H_ELEMS, mode);
    }
    (void)in_sizes; (void)n_in; (void)ws_size; (void)d_in;
}